// Round 10
// baseline (205.830 us; speedup 1.0000x reference)
//
#include <hip/hip_runtime.h>
#include <stdint.h>

#define EMB 512
#define SEQ 2048
#define MB 4
#define NH 8
#define HD 64
#define ROWS (MB*SEQ)          // 8192
#define MARGIN 0.02f
#define CAP 65536
#define LOG2E 1.44269504f
#define EXPB (-17.3123405f)    // -12 * log2(e)

typedef unsigned short u16;
typedef __attribute__((ext_vector_type(8))) short bf16x8;   // 8 bf16 (4 VGPRs)
typedef __attribute__((ext_vector_type(4))) float f32x4;
typedef __attribute__((ext_vector_type(2))) unsigned int u32x2;
typedef __attribute__((ext_vector_type(4))) unsigned int u32x4;

union Frag { u32x2 u[2]; bf16x8 v; };
union Frag4 { unsigned u[4]; bf16x8 v; };

__device__ __forceinline__ u16 f2bf(float f) {
  union { float f; unsigned u; } a; a.f = f;
  unsigned r = a.u + 0x7FFFu + ((a.u >> 16) & 1u);  // RNE
  return (u16)(r >> 16);
}
__device__ __forceinline__ float bflo(unsigned u) {
  union { unsigned u; float f; } c; c.u = u << 16; return c.f;
}
__device__ __forceinline__ float bfhi(unsigned u) {
  union { unsigned u; float f; } c; c.u = u & 0xffff0000u; return c.f;
}
__device__ __forceinline__ float b2f(u16 h) {
  union { unsigned u; float f; } c; c.u = (unsigned)h << 16; return c.f;
}
// async global->LDS, 16B per lane; LDS dest = wave-uniform base + lane*16
__device__ __forceinline__ void gld16(const void* g, void* l) {
  __builtin_amdgcn_global_load_lds(
      (const __attribute__((address_space(1))) void*)g,
      (__attribute__((address_space(3))) void*)l, 16, 0, 0);
}

// ---------------- fused prep: 4 weight transposes (blocks 0..1791) + LN1 (1792..3839) ----
// wk is pre-scaled by LOG2E (flash folds softmax's s*LOG2E into K itself).

__global__ __launch_bounds__(256) void k_prep(
    const float* __restrict__ x, const float* __restrict__ g1, const float* __restrict__ be1,
    const float* __restrict__ wq, const float* __restrict__ wk,
    const float* __restrict__ wv, const float* __restrict__ w1,
    u16* __restrict__ n1, u16* __restrict__ wqkvT, u16* __restrict__ w1T,
    int* __restrict__ cnt) {
  __shared__ float tile[32][33];
  int b = blockIdx.x, tid = threadIdx.x;
  if (b < 1792) {
    const float* src; u16* dst; int N, bx, by;
    float scl = 1.0f;
    if (b < 768) {
      int z = b >> 8, rem = b & 255; bx = rem & 15; by = rem >> 4; N = 512;
      src = (z == 0) ? wq : ((z == 1) ? wk : wv);
      if (z == 1) scl = LOG2E;
      dst = wqkvT + z * 512 * 512;
    } else {
      int rem = b - 768; bx = rem & 63; by = rem >> 6; N = 2048;
      src = w1; dst = w1T;
    }
    int tx = tid & 31, ty = tid >> 5;
    int k0 = by * 32, n0 = bx * 32;
    for (int i = 0; i < 32; i += 8)
      tile[ty + i][tx] = src[(size_t)(k0 + ty + i) * N + n0 + tx];
    __syncthreads();
    for (int i = 0; i < 32; i += 8)
      dst[(size_t)(n0 + ty + i) * 512 + k0 + tx] = f2bf(tile[tx][ty + i] * scl);
  } else {
    if (b == 1792 && tid < 2) cnt[tid] = 0;
    int wid = tid >> 6, lane = tid & 63;
    int row = (b - 1792) * 4 + wid;
    const float* xr = x + (size_t)row * EMB + lane * 8;
    f32x4 v0 = *(const f32x4*)xr;
    f32x4 v1 = *(const f32x4*)(xr + 4);
    float s = v0.x+v0.y+v0.z+v0.w + v1.x+v1.y+v1.z+v1.w;
    float q = v0.x*v0.x+v0.y*v0.y+v0.z*v0.z+v0.w*v0.w
            + v1.x*v1.x+v1.y*v1.y+v1.z*v1.z+v1.w*v1.w;
    #pragma unroll
    for (int o = 1; o < 64; o <<= 1) { s += __shfl_xor(s, o); q += __shfl_xor(q, o); }
    float mu = s * (1.0f/512.0f);
    float rs = 1.0f / sqrtf(q * (1.0f/512.0f) - mu*mu + 1e-5f);
    f32x4 ga = *(const f32x4*)(g1 + lane*8), gb = *(const f32x4*)(g1 + lane*8 + 4);
    f32x4 ba = *(const f32x4*)(be1 + lane*8), bb = *(const f32x4*)(be1 + lane*8 + 4);
    union { u16 h[8]; u32x4 v; } o8;
    o8.h[0] = f2bf((v0.x-mu)*rs*ga.x + ba.x); o8.h[1] = f2bf((v0.y-mu)*rs*ga.y + ba.y);
    o8.h[2] = f2bf((v0.z-mu)*rs*ga.z + ba.z); o8.h[3] = f2bf((v0.w-mu)*rs*ga.w + ba.w);
    o8.h[4] = f2bf((v1.x-mu)*rs*gb.x + bb.x); o8.h[5] = f2bf((v1.y-mu)*rs*gb.y + bb.y);
    o8.h[6] = f2bf((v1.z-mu)*rs*gb.z + bb.z); o8.h[7] = f2bf((v1.w-mu)*rs*gb.w + bb.w);
    *(u32x4*)(n1 + (size_t)row * EMB + lane * 8) = o8.v;
  }
}

// x2 = x + (u0+u1)/(l0+l1) (not materialized; fixup recomputes); n2 = LN(x2); out = x2+b2
__global__ __launch_bounds__(256) void k_ln2(const float* __restrict__ x,
    const u16* __restrict__ att0, const u16* __restrict__ att1,
    const float* __restrict__ l0, const float* __restrict__ l1,
    const float* __restrict__ g, const float* __restrict__ b,
    const float* __restrict__ b2, u16* __restrict__ n2,
    float* __restrict__ out) {
  int wid = threadIdx.x >> 6, lane = threadIdx.x & 63;
  int row = blockIdx.x * 4 + wid;
  size_t base = (size_t)row * EMB + lane * 8;
  int mm = row >> 11, qq = row & 2047, head = lane >> 3;   // lane's 8 cols in one head
  size_t li = (size_t)(mm * 8 + head) * SEQ + qq;
  float rl = 1.0f / (l0[li] + l1[li]);
  u32x4 a0 = *(const u32x4*)(att0 + base);
  u32x4 a1 = *(const u32x4*)(att1 + base);
  f32x4 t0, t1;
  t0.x = (bflo(a0.x) + bflo(a1.x)) * rl; t0.y = (bfhi(a0.x) + bfhi(a1.x)) * rl;
  t0.z = (bflo(a0.y) + bflo(a1.y)) * rl; t0.w = (bfhi(a0.y) + bfhi(a1.y)) * rl;
  t1.x = (bflo(a0.z) + bflo(a1.z)) * rl; t1.y = (bfhi(a0.z) + bfhi(a1.z)) * rl;
  t1.z = (bflo(a0.w) + bflo(a1.w)) * rl; t1.w = (bfhi(a0.w) + bfhi(a1.w)) * rl;
  f32x4 v0 = *(const f32x4*)(x + base)     + t0;
  f32x4 v1 = *(const f32x4*)(x + base + 4) + t1;
  *(f32x4*)(out + base)     = v0 + *(const f32x4*)(b2 + lane*8);
  *(f32x4*)(out + base + 4) = v1 + *(const f32x4*)(b2 + lane*8 + 4);
  float s = v0.x+v0.y+v0.z+v0.w + v1.x+v1.y+v1.z+v1.w;
  float q = v0.x*v0.x+v0.y*v0.y+v0.z*v0.z+v0.w*v0.w
          + v1.x*v1.x+v1.y*v1.y+v1.z*v1.z+v1.w*v1.w;
  #pragma unroll
  for (int o = 1; o < 64; o <<= 1) { s += __shfl_xor(s, o); q += __shfl_xor(q, o); }
  float mu = s * (1.0f/512.0f);
  float rs = 1.0f / sqrtf(q * (1.0f/512.0f) - mu*mu + 1e-5f);
  f32x4 ga = *(const f32x4*)(g + lane*8), gb = *(const f32x4*)(g + lane*8 + 4);
  f32x4 ba = *(const f32x4*)(b + lane*8), bb = *(const f32x4*)(b + lane*8 + 4);
  union { u16 h[8]; u32x4 v; } o8;
  o8.h[0] = f2bf((v0.x-mu)*rs*ga.x + ba.x); o8.h[1] = f2bf((v0.y-mu)*rs*ga.y + ba.y);
  o8.h[2] = f2bf((v0.z-mu)*rs*ga.z + ba.z); o8.h[3] = f2bf((v0.w-mu)*rs*ga.w + ba.w);
  o8.h[4] = f2bf((v1.x-mu)*rs*gb.x + bb.x); o8.h[5] = f2bf((v1.y-mu)*rs*gb.y + bb.y);
  o8.h[6] = f2bf((v1.z-mu)*rs*gb.z + bb.z); o8.h[7] = f2bf((v1.w-mu)*rs*gb.w + bb.w);
  *(u32x4*)(n2 + (size_t)row * EMB + lane * 8) = o8.v;
}

// -------- GEMM core (r6-proven): 32KB dbuf, 1 barrier/tile, ~5 blocks/CU --------
#define GEMM_CORE(A_, Bt_, m0_, n0_)                                           \
  __shared__ u16 As[2][128 * 32];                                              \
  __shared__ u16 Bs[2][128 * 32];                                              \
  int tid = threadIdx.x;                                                       \
  int wid = tid >> 6, lane = tid & 63;                                         \
  int quad = lane >> 4, ln15 = lane & 15;                                      \
  int wm = (wid >> 1) * 64, wn = (wid & 1) * 64;                               \
  int arow = lane >> 2, acol = (lane & 3) * 8;                                 \
  const u16* gA0 = A_  + (size_t)(m0_ + wid * 32 + arow) * 512 + acol;         \
  const u16* gA1 = gA0 + (size_t)16 * 512;                                     \
  const u16* gB0 = Bt_ + (size_t)(n0_ + wid * 32 + arow) * 512 + acol;         \
  const u16* gB1 = gB0 + (size_t)16 * 512;                                     \
  f32x4 acc[4][4] = {};                                                        \
  gld16(gA0, &As[0][(wid * 32) * 32]); gld16(gA1, &As[0][(wid * 32 + 16) * 32]);\
  gld16(gB0, &Bs[0][(wid * 32) * 32]); gld16(gB1, &Bs[0][(wid * 32 + 16) * 32]);\
  for (int kt = 0; kt < 16; kt++) {                                            \
    int cur = kt & 1;                                                          \
    __syncthreads();                                                           \
    if (kt < 15) {                                                             \
      int ko = (kt + 1) * 32;                                                  \
      gld16(gA0 + ko, &As[cur ^ 1][(wid * 32) * 32]);                          \
      gld16(gA1 + ko, &As[cur ^ 1][(wid * 32 + 16) * 32]);                     \
      gld16(gB0 + ko, &Bs[cur ^ 1][(wid * 32) * 32]);                          \
      gld16(gB1 + ko, &Bs[cur ^ 1][(wid * 32 + 16) * 32]);                     \
    }                                                                          \
    bf16x8 af[4], bf[4];                                                       \
    _Pragma("unroll")                                                          \
    for (int i = 0; i < 4; i++) {                                              \
      af[i] = *(const bf16x8*)&As[cur][(wm + i * 16 + ln15) * 32 + quad * 8];  \
      bf[i] = *(const bf16x8*)&Bs[cur][(wn + i * 16 + ln15) * 32 + quad * 8];  \
    }                                                                          \
    _Pragma("unroll")                                                          \
    for (int i = 0; i < 4; i++)                                                \
      _Pragma("unroll")                                                        \
      for (int j = 0; j < 4; j++)                                              \
        acc[i][j] = __builtin_amdgcn_mfma_f32_16x16x32_bf16(af[i], bf[j],      \
                                                            acc[i][j], 0, 0, 0);\
  }                                                                            \
  __syncthreads();

// QKV: A=n1 [8192][512], Bt=wqkvT [1536][512]; scatter to Q/K [mh][s][d], Vt [mh][d][s]
// XCD swizzle (T1, r5-proven); K bias scaled by LOG2E.
__global__ __launch_bounds__(256) void k_gemm_qkv(
    const u16* __restrict__ A, const u16* __restrict__ Bt,
    const float* __restrict__ bq, const float* __restrict__ bk, const float* __restrict__ bv,
    u16* __restrict__ Qb, u16* __restrict__ Kb, u16* __restrict__ Vtb) {
  int bid = blockIdx.x + 12 * blockIdx.y;          // dispatch id, 0..767
  int c = bid & 7, r = bid >> 3;                   // XCD c, 96 blocks each
  int m0 = (c * 8 + r / 12) * 128, n0 = (r % 12) * 128;
  GEMM_CORE(A, Bt, m0, n0)
  #pragma unroll
  for (int j = 0; j < 4; j++) {
    int n = n0 + wn + j * 16 + ln15;          // uniform t within 16-lane group
    int t = n >> 9, cc = n & 511, head = cc >> 6, dd = cc & 63;
    float bias = (t == 0) ? bq[cc] : ((t == 1) ? bk[cc] * LOG2E : bv[cc]);
    #pragma unroll
    for (int i = 0; i < 4; i++) {
      int row0 = m0 + wm + i * 16 + quad * 4;
      int mm = row0 >> 11, ss0 = row0 & 2047;
      if (t == 2) {
        union { u16 h[4]; u32x2 v; } pk;
        #pragma unroll
        for (int r2 = 0; r2 < 4; r2++) pk.h[r2] = f2bf(acc[i][j][r2] + bias);
        *(u32x2*)(Vtb + ((size_t)(mm * 8 + head) * 64 + dd) * 2048 + ss0) = pk.v;
      } else {
        u16* dst = (t == 0) ? Qb : Kb;
        #pragma unroll
        for (int r2 = 0; r2 < 4; r2++)
          dst[((size_t)(mm * 8 + head) * 2048 + ss0 + r2) * 64 + dd] =
              f2bf(acc[i][j][r2] + bias);
      }
    }
  }
}

// FFN1: A=n2 [8192][512], Bt=w1T [2048][512]; spike/candidate lists only
__global__ __launch_bounds__(256) void k_gemm_ffn1(
    const u16* __restrict__ A, const u16* __restrict__ Bt, const float* __restrict__ b1,
    int* __restrict__ cnt, unsigned* __restrict__ spikeL, unsigned* __restrict__ candL) {
  int bid = blockIdx.x + 16 * blockIdx.y;          // dispatch id, 0..1023
  int c = bid & 7, r = bid >> 3;                   // XCD c, 128 blocks each
  int m0 = (c * 8 + r / 16) * 128, n0 = (r % 16) * 128;
  GEMM_CORE(A, Bt, m0, n0)
  #pragma unroll
  for (int j = 0; j < 4; j++) {
    int n = n0 + wn + j * 16 + ln15;
    float bias = b1[n];
    #pragma unroll
    for (int i = 0; i < 4; i++) {
      #pragma unroll
      for (int r2 = 0; r2 < 4; r2++) {
        int row = m0 + wm + i * 16 + quad * 4 + r2;
        float hv = acc[i][j][r2] + bias;
        if (hv >= 2.0f - MARGIN) {
          if (hv >= 2.0f + MARGIN) {
            int ix = atomicAdd(&cnt[0], 1);
            if (ix < CAP) spikeL[ix] = (unsigned)(row * 2048 + n);
          } else {
            int ix = atomicAdd(&cnt[1], 1);
            if (ix < CAP) candL[ix] = (unsigned)(row * 2048 + n);
          }
        }
      }
    }
  }
}

// ------- flash v16: kv-split, split-buffer plain stores (no atomics, no memset) ----
// v15 failed (absmax 0.727, out ~468 = garbage-scale): suspects were the
// hipMemsetAsync-seeded Uacc under graph capture and/or the atomic combine.
// v16 keeps the kv-split occupancy experiment (32 q/wave, 32KB LDS, grid 1024
// -> 4 blocks x 4 waves = 16 waves/CU) but each kvh block PLAIN-stores its
// unnormalized U-half (bf16, att0/att1) and l-half (f32, l0/l1) -- each element
// written exactly once (v13's proven epilogue store path minus *rl). ln2/fixup
// combine: att = (u0+u1)/(l0+l1). Exact math: fixed EXPB shift, no running max.
#define F_STAGE(BUF, T0)                                                       \
  do {                                                                         \
    gld16(gK0 + (size_t)(T0) * 4096, &L.SB[BUF][0][rb0 * 64]);                 \
    gld16(gK1 + (size_t)(T0) * 4096, &L.SB[BUF][0][rb1 * 64]);                 \
    gld16(gV0 + (T0) * 64, &L.SB[BUF][1][rb0 * 64]);                           \
    gld16(gV1 + (T0) * 64, &L.SB[BUF][1][rb1 * 64]);                           \
  } while (0)

#define F_INNER(BUF)                                                           \
  do {                                                                         \
    const u16* Kc = L.SB[BUF][0];                                              \
    const u16* Vc = L.SB[BUF][1];                                              \
    f32x4 s4[2][4];                                                            \
    __builtin_amdgcn_s_setprio(1);                                             \
    _Pragma("unroll")                                                          \
    for (int j = 0; j < 4; j++) {                                              \
      bf16x8 a = *(const bf16x8*)(Kc + (j * 16 + ln15) * 64 + ((quad ^ lm) * 8)); \
      s4[0][j] = __builtin_amdgcn_mfma_f32_16x16x32_bf16(a, aQ[0][0].v, e4, 0, 0, 0); \
      s4[1][j] = __builtin_amdgcn_mfma_f32_16x16x32_bf16(a, aQ[1][0].v, e4, 0, 0, 0); \
    }                                                                          \
    _Pragma("unroll")                                                          \
    for (int j = 0; j < 4; j++) {                                              \
      bf16x8 a = *(const bf16x8*)(Kc + (j * 16 + ln15) * 64 + (((4 + quad) ^ lm) * 8)); \
      s4[0][j] = __builtin_amdgcn_mfma_f32_16x16x32_bf16(a, aQ[0][1].v, s4[0][j], 0, 0, 0); \
      s4[1][j] = __builtin_amdgcn_mfma_f32_16x16x32_bf16(a, aQ[1][1].v, s4[1][j], 0, 0, 0); \
    }                                                                          \
    __builtin_amdgcn_s_setprio(0);                                             \
    Frag4 bP[2][2];                                                            \
    _Pragma("unroll")                                                          \
    for (int h = 0; h < 2; h++) {                                              \
      unsigned pr[4][4];                                                       \
      _Pragma("unroll")                                                        \
      for (int j = 0; j < 4; j++)                                              \
        _Pragma("unroll")                                                      \
        for (int r = 0; r < 4; r++) {                                          \
          float p = __builtin_amdgcn_exp2f(s4[h][j][r]);                       \
          union { float f; unsigned u; } cc; cc.f = p;                         \
          pr[j][r] = cc.u;                                                     \
        }                                                                      \
      _Pragma("unroll")                                                        \
      for (int t = 0; t < 2; t++) {                                            \
        bP[h][t].u[0] = __builtin_amdgcn_perm(pr[2*t][1],   pr[2*t][0],   0x07060302u); \
        bP[h][t].u[1] = __builtin_amdgcn_perm(pr[2*t][3],   pr[2*t][2],   0x07060302u); \
        bP[h][t].u[2] = __builtin_amdgcn_perm(pr[2*t+1][1], pr[2*t+1][0], 0x07060302u); \
        bP[h][t].u[3] = __builtin_amdgcn_perm(pr[2*t+1][3], pr[2*t+1][2], 0x07060302u); \
      }                                                                        \
    }                                                                          \
    __builtin_amdgcn_s_setprio(1);                                             \
    lacc[0] = __builtin_amdgcn_mfma_f32_16x16x32_bf16(vOne.v, bP[0][0].v, lacc[0], 0, 0, 0); \
    lacc[1] = __builtin_amdgcn_mfma_f32_16x16x32_bf16(vOne.v, bP[1][0].v, lacc[1], 0, 0, 0); \
    lacc[0] = __builtin_amdgcn_mfma_f32_16x16x32_bf16(vOne.v, bP[0][1].v, lacc[0], 0, 0, 0); \
    lacc[1] = __builtin_amdgcn_mfma_f32_16x16x32_bf16(vOne.v, bP[1][1].v, lacc[1], 0, 0, 0); \
    _Pragma("unroll")                                                          \
    for (int t = 0; t < 2; t++)                                                \
      _Pragma("unroll")                                                        \
      for (int j = 0; j < 4; j++) {                                            \
        int row = j * 16 + ln15;                                               \
        int c0 = 4 * t + (quad >> 1), sub = (quad & 1) * 4;                    \
        Frag aV;                                                               \
        aV.u[0] = *(const u32x2*)(Vc + row * 64 + ((c0 ^ lm) * 8) + sub);      \
        aV.u[1] = *(const u32x2*)(Vc + row * 64 + (((c0 + 2) ^ lm) * 8) + sub);\
        U[0][j] = __builtin_amdgcn_mfma_f32_16x16x32_bf16(aV.v, bP[0][t].v,    \
                                                          U[0][j], 0, 0, 0);   \
        U[1][j] = __builtin_amdgcn_mfma_f32_16x16x32_bf16(aV.v, bP[1][t].v,    \
                                                          U[1][j], 0, 0, 0);   \
      }                                                                        \
    __builtin_amdgcn_s_setprio(0);                                             \
  } while (0)

__global__ __launch_bounds__(256, 4) void k_flash(
    const u16* __restrict__ Q, const u16* __restrict__ K,
    const u16* __restrict__ Vt, u16* __restrict__ att0, u16* __restrict__ att1,
    float* __restrict__ l0, float* __restrict__ l1) {
  __shared__ union {
    u16 SB[2][2][64 * 64];   // [buf][K/V][64 rows][64 u16 chunk-swizzled] 32 KB
    float T[4][16 * 68];     // per-wave epilogue transpose (after final barrier)
  } L;
  int tid = threadIdx.x, wid = tid >> 6, lane = tid & 63;
  int quad = lane >> 4, ln15 = lane & 15, lm = ln15 & 7;
  // bijective XCD swizzle: XCD c owns swz [c*128,(c+1)*128) = 4 complete
  // (head,mm) groups (16 qb x 2 kv-halves each) -> K/V + att rows L2-local.
  int bid = blockIdx.x + 32 * (blockIdx.y + 8 * (int)blockIdx.z);
  int swz = (bid & 7) * 128 + (bid >> 3);
  int kvh = swz & 1, qb = (swz >> 1) & 15, head = (swz >> 5) & 7, mm = swz >> 8;
  int mh = mm * 8 + head;
  const u16* Qp = Q  + (size_t)mh * SEQ * HD;
  const u16* Kp = K  + (size_t)mh * SEQ * HD + (size_t)kvh * 1024 * HD;
  const u16* Vp = Vt + (size_t)mh * HD * SEQ + kvh * 1024;
  u16*  attH = kvh ? att1 : att0;
  float* lH  = kvh ? l1 : l0;
  int q0 = qb * 128 + wid * 32;

  Frag aQ[2][2];   // [q-half][t]: B-operand Q[q=ln15][d=t*32+quad*8+..]
  #pragma unroll
  for (int h = 0; h < 2; h++)
    #pragma unroll
    for (int t = 0; t < 2; t++) {
      u32x4 g = *(const u32x4*)(Qp + (size_t)(q0 + h * 16 + ln15) * 64 + t * 32 + quad * 8);
      aQ[h][t].u[0].x = g.x; aQ[h][t].u[0].y = g.y;
      aQ[h][t].u[1].x = g.z; aQ[h][t].u[1].y = g.w;
    }
  const f32x4 e4 = {EXPB, EXPB, EXPB, EXPB};   // QK C-init: s4 = K~.Q + EXPB
  Frag4 vOne;      // bf16 1.0 x8 (A-operand for l-sum MFMA)
  vOne.u[0] = 0x3F803F80u; vOne.u[1] = 0x3F803F80u;
  vOne.u[2] = 0x3F803F80u; vOne.u[3] = 0x3F803F80u;

  // staging: lane -> (row l>>3, phys chunk l&7) holds global chunk (l&7)^(l>>3&7)
  int srow = lane >> 3;
  int sch  = (lane & 7) ^ (srow & 7);
  int rb0 = wid * 16, rb1 = wid * 16 + 8;
  const u16* gK0 = Kp + (size_t)(rb0 + srow) * 64 + sch * 8;
  const u16* gK1 = Kp + (size_t)(rb1 + srow) * 64 + sch * 8;
  const u16* gV0 = Vp + (size_t)(rb0 + srow) * SEQ + sch * 8;
  const u16* gV1 = Vp + (size_t)(rb1 + srow) * SEQ + sch * 8;

  f32x4 lacc[2] = {};          // [q-half]: every reg/row = sum_k P[k][q=ln15]
  f32x4 U[2][4] = {};          // [q-half][j]: U^T[d=j*16+quad*4+r][q=ln15]

  F_STAGE(0, 0);
  for (int s = 0; s < 16; s++) {
    __syncthreads();
    if (s < 15) F_STAGE((s & 1) ^ 1, s + 1);
    F_INNER(s & 1);
  }
  __syncthreads();   // protect T-union from other waves' last-step LDS reads

  #pragma unroll
  for (int h = 0; h < 2; h++) {
    if (quad == 0)
      lH[(size_t)mh * SEQ + q0 + h * 16 + ln15] = lacc[h][0];
    float* Tw = L.T[wid];
    #pragma unroll
    for (int j = 0; j < 4; j++)
      *(f32x4*)(Tw + ln15 * 68 + j * 16 + quad * 4) = U[h][j];
    #pragma unroll
    for (int s2 = 0; s2 < 4; s2++) {
      f32x4 o = *(const f32x4*)(Tw + (quad * 4 + s2) * 68 + ln15 * 4);
      union { u16 h4[4]; u32x2 v; } pk;
      pk.h4[0] = f2bf(o.x); pk.h4[1] = f2bf(o.y);
      pk.h4[2] = f2bf(o.z); pk.h4[3] = f2bf(o.w);
      *(u32x2*)(attH + ((size_t)mm * SEQ + q0 + h * 16 + quad * 4 + s2) * EMB +
                head * 64 + ln15 * 4) = pk.v;
    }
  }
}

// exact fp32 recompute of borderline h1 entries; append true spikes.
// x2 reconstructed as x + (u0+u1)/(l0+l1) -- same op sequence as k_ln2.
__global__ __launch_bounds__(256) void k_fixup(
    const float* __restrict__ x, const u16* __restrict__ att0,
    const u16* __restrict__ att1,
    const float* __restrict__ l0, const float* __restrict__ l1,
    const float* __restrict__ w1, const float* __restrict__ b1,
    const float* __restrict__ g2, const float* __restrict__ be2,
    int* __restrict__ cnt, unsigned* __restrict__ spikeL, const unsigned* __restrict__ candL) {
  __shared__ float sb[8];
  int tid = threadIdx.x;
  int nC = cnt[1]; if (nC > CAP) nC = CAP;
  for (int e = blockIdx.x; e < nC; e += gridDim.x) {
    unsigned v = candL[e];
    int row = (int)(v >> 11), col = (int)(v & 2047u);
    int mm = row >> 11, qq = row & 2047;
    const float* xr = x + (size_t)row * 512;
    const u16* a0r = att0 + (size_t)row * 512;
    const u16* a1r = att1 + (size_t)row * 512;
    size_t li0 = (size_t)(mm * 8 + (tid >> 6)) * SEQ + qq;
    size_t li1 = (size_t)(mm * 8 + ((tid + 256) >> 6)) * SEQ + qq;
    float rl0 = 1.0f / (l0[li0] + l1[li0]);
    float rl1 = 1.0f / (l0[li1] + l1[li1]);
    float x0 = xr[tid] + (b2f(a0r[tid]) + b2f(a1r[tid])) * rl0;
    float x1 = xr[tid + 256] + (b2f(a0r[tid + 256]) + b2f(a1r[tid + 256])) * rl1;
    float s = x0 + x1, q = x0 * x0 + x1 * x1;
    #pragma unroll
    for (int o = 1; o < 64; o <<= 1) { s += __shfl_xor(s, o); q += __shfl_xor(q, o); }
    if ((tid & 63) == 0) { sb[tid >> 6] = s; sb[4 + (tid >> 6)] = q; }
    __syncthreads();
    float st = sb[0] + sb[1] + sb[2] + sb[3];
    float qt = sb[4] + sb[5] + sb[6] + sb[7];
    __syncthreads();
    float mu = st * (1.f / 512.f);
    float rs = 1.f / sqrtf(qt * (1.f / 512.f) - mu * mu + 1e-5f);
    float na = (x0 - mu) * rs * g2[tid] + be2[tid];
    float nb = (x1 - mu) * rs * g2[tid + 256] + be2[tid + 256];
    float dd = na * w1[(size_t)tid * 2048 + col] + nb * w1[(size_t)(tid + 256) * 2048 + col];
    #pragma unroll
    for (int o = 1; o < 64; o <<= 1) dd += __shfl_xor(dd, o);
    if ((tid & 63) == 0) sb[tid >> 6] = dd;
    __syncthreads();
    if (tid == 0) {
      float hv = sb[0] + sb[1] + sb[2] + sb[3] + b1[col];
      if (hv >= 2.0f) { int ix = atomicAdd(&cnt[0], 1); if (ix < CAP) spikeL[ix] = v; }
    }
    __syncthreads();
  }
}

// out[row,:] += w2[col,:] for each spike
__global__ void k_apply(const float* __restrict__ w2, const int* __restrict__ cnt,
                        const unsigned* __restrict__ spikeL, float* __restrict__ out) {
  int n = cnt[0]; if (n > CAP) n = CAP;
  int tid = threadIdx.x;
  for (int e = blockIdx.x; e < n; e += gridDim.x) {
    unsigned v = spikeL[e];
    int row = (int)(v >> 11), col = (int)(v & 2047u);
    atomicAdd(&out[(size_t)row * 512 + tid * 2 + 0], w2[(size_t)col * 512 + tid * 2 + 0]);
    atomicAdd(&out[(size_t)row * 512 + tid * 2 + 1], w2[(size_t)col * 512 + tid * 2 + 1]);
  }
}

// ---------------- launch ----------------

extern "C" void kernel_launch(void* const* d_in, const int* in_sizes, int n_in,
                              void* d_out, int out_size, void* d_ws, size_t ws_size,
                              hipStream_t stream) {
  (void)in_sizes; (void)n_in; (void)out_size; (void)ws_size;
  const float* x   = (const float*)d_in[0];
  const float* wq  = (const float*)d_in[1];
  const float* bq  = (const float*)d_in[2];
  const float* wk  = (const float*)d_in[3];
  const float* bk  = (const float*)d_in[4];
  const float* wv  = (const float*)d_in[5];
  const float* bv  = (const float*)d_in[6];
  const float* w1  = (const float*)d_in[7];
  const float* b1  = (const float*)d_in[8];
  const float* w2  = (const float*)d_in[9];
  const float* b2  = (const float*)d_in[10];
  const float* g1  = (const float*)d_in[11];
  const float* be1 = (const float*)d_in[12];
  const float* g2  = (const float*)d_in[13];
  const float* be2 = (const float*)d_in[14];
  float* out = (float*)d_out;

  char* w = (char*)d_ws;
  size_t off = 0;
  auto take = [&](size_t bytes) { char* p = w + off; off += (bytes + 255) & ~(size_t)255; return p; };
  int*      cnt    = (int*)take(256);
  u16*      n1     = (u16*)take((size_t)ROWS * EMB * 2);
  u16*      wqkvT  = (u16*)take((size_t)1536 * 512 * 2);
  u16*      w1T    = (u16*)take((size_t)2048 * 512 * 2);
  u16*      Qb     = (u16*)take((size_t)MB * NH * SEQ * HD * 2);
  u16*      Kb     = (u16*)take((size_t)MB * NH * SEQ * HD * 2);
  u16*      Vtb    = (u16*)take((size_t)MB * NH * SEQ * HD * 2);
  u16*      att0   = (u16*)take((size_t)ROWS * EMB * 2);          // U half 0 (bf16)
  u16*      att1   = (u16*)take((size_t)ROWS * EMB * 2);          // U half 1 (bf16)
  float*    l0     = (float*)take((size_t)MB * NH * SEQ * 4);     // l half 0
  float*    l1     = (float*)take((size_t)MB * NH * SEQ * 4);     // l half 1
  u16*      n2     = (u16*)take((size_t)ROWS * EMB * 2);
  unsigned* spikeL = (unsigned*)take((size_t)CAP * 4);
  unsigned* candL  = (unsigned*)take((size_t)CAP * 4);

  k_prep<<<3840, 256, 0, stream>>>(x, g1, be1, wq, wk, wv, w1, n1, wqkvT, w1T, cnt);
  k_gemm_qkv<<<dim3(12, 64), 256, 0, stream>>>(n1, wqkvT, bq, bk, bv, Qb, Kb, Vtb);
  k_flash<<<dim3(32, 8, 4), 256, 0, stream>>>(Qb, Kb, Vtb, att0, att1, l0, l1);
  k_ln2<<<ROWS / 4, 256, 0, stream>>>(x, att0, att1, l0, l1, g2, be2, b2, n2, out);
  k_gemm_ffn1<<<dim3(16, 64), 256, 0, stream>>>(n2, w1T, b1, cnt, spikeL, candL);
  k_fixup<<<256, 256, 0, stream>>>(x, att0, att1, l0, l1, w1, b1, g2, be2, cnt, spikeL, candL);
  k_apply<<<128, 256, 0, stream>>>(w2, cnt, spikeL, out);
}

// Round 11
// 205.536 us; speedup vs baseline: 1.0014x; 1.0014x over previous
//
#include <hip/hip_runtime.h>
#include <stdint.h>

#define EMB 512
#define SEQ 2048
#define MB 4
#define NH 8
#define HD 64
#define ROWS (MB*SEQ)          // 8192
#define MARGIN 0.02f
#define CAP 65536
#define LOG2E 1.44269504f
#define EXPB (-17.3123405f)    // -12 * log2(e)

typedef unsigned short u16;
typedef __attribute__((ext_vector_type(8))) short bf16x8;   // 8 bf16 (4 VGPRs)
typedef __attribute__((ext_vector_type(4))) float f32x4;
typedef __attribute__((ext_vector_type(2))) unsigned int u32x2;
typedef __attribute__((ext_vector_type(4))) unsigned int u32x4;

union Frag { u32x2 u[2]; bf16x8 v; };
union Frag4 { unsigned u[4]; bf16x8 v; };

__device__ __forceinline__ u16 f2bf(float f) {
  union { float f; unsigned u; } a; a.f = f;
  unsigned r = a.u + 0x7FFFu + ((a.u >> 16) & 1u);  // RNE
  return (u16)(r >> 16);
}
__device__ __forceinline__ float bflo(unsigned u) {
  union { unsigned u; float f; } c; c.u = u << 16; return c.f;
}
__device__ __forceinline__ float bfhi(unsigned u) {
  union { unsigned u; float f; } c; c.u = u & 0xffff0000u; return c.f;
}
__device__ __forceinline__ float b2f(u16 h) {
  union { unsigned u; float f; } c; c.u = (unsigned)h << 16; return c.f;
}
// async global->LDS, 16B per lane; LDS dest = wave-uniform base + lane*16
__device__ __forceinline__ void gld16(const void* g, void* l) {
  __builtin_amdgcn_global_load_lds(
      (const __attribute__((address_space(1))) void*)g,
      (__attribute__((address_space(3))) void*)l, 16, 0, 0);
}

// ---------------- fused prep: 4 weight transposes (blocks 0..1791) + LN1 (1792..3839) ----
// wk is pre-scaled by LOG2E (flash folds softmax's s*LOG2E into K itself).

__global__ __launch_bounds__(256) void k_prep(
    const float* __restrict__ x, const float* __restrict__ g1, const float* __restrict__ be1,
    const float* __restrict__ wq, const float* __restrict__ wk,
    const float* __restrict__ wv, const float* __restrict__ w1,
    u16* __restrict__ n1, u16* __restrict__ wqkvT, u16* __restrict__ w1T,
    int* __restrict__ cnt) {
  __shared__ float tile[32][33];
  int b = blockIdx.x, tid = threadIdx.x;
  if (b < 1792) {
    const float* src; u16* dst; int N, bx, by;
    float scl = 1.0f;
    if (b < 768) {
      int z = b >> 8, rem = b & 255; bx = rem & 15; by = rem >> 4; N = 512;
      src = (z == 0) ? wq : ((z == 1) ? wk : wv);
      if (z == 1) scl = LOG2E;
      dst = wqkvT + z * 512 * 512;
    } else {
      int rem = b - 768; bx = rem & 63; by = rem >> 6; N = 2048;
      src = w1; dst = w1T;
    }
    int tx = tid & 31, ty = tid >> 5;
    int k0 = by * 32, n0 = bx * 32;
    for (int i = 0; i < 32; i += 8)
      tile[ty + i][tx] = src[(size_t)(k0 + ty + i) * N + n0 + tx];
    __syncthreads();
    for (int i = 0; i < 32; i += 8)
      dst[(size_t)(n0 + ty + i) * 512 + k0 + tx] = f2bf(tile[tx][ty + i] * scl);
  } else {
    if (b == 1792 && tid < 2) cnt[tid] = 0;
    int wid = tid >> 6, lane = tid & 63;
    int row = (b - 1792) * 4 + wid;
    const float* xr = x + (size_t)row * EMB + lane * 8;
    f32x4 v0 = *(const f32x4*)xr;
    f32x4 v1 = *(const f32x4*)(xr + 4);
    float s = v0.x+v0.y+v0.z+v0.w + v1.x+v1.y+v1.z+v1.w;
    float q = v0.x*v0.x+v0.y*v0.y+v0.z*v0.z+v0.w*v0.w
            + v1.x*v1.x+v1.y*v1.y+v1.z*v1.z+v1.w*v1.w;
    #pragma unroll
    for (int o = 1; o < 64; o <<= 1) { s += __shfl_xor(s, o); q += __shfl_xor(q, o); }
    float mu = s * (1.0f/512.0f);
    float rs = 1.0f / sqrtf(q * (1.0f/512.0f) - mu*mu + 1e-5f);
    f32x4 ga = *(const f32x4*)(g1 + lane*8), gb = *(const f32x4*)(g1 + lane*8 + 4);
    f32x4 ba = *(const f32x4*)(be1 + lane*8), bb = *(const f32x4*)(be1 + lane*8 + 4);
    union { u16 h[8]; u32x4 v; } o8;
    o8.h[0] = f2bf((v0.x-mu)*rs*ga.x + ba.x); o8.h[1] = f2bf((v0.y-mu)*rs*ga.y + ba.y);
    o8.h[2] = f2bf((v0.z-mu)*rs*ga.z + ba.z); o8.h[3] = f2bf((v0.w-mu)*rs*ga.w + ba.w);
    o8.h[4] = f2bf((v1.x-mu)*rs*gb.x + bb.x); o8.h[5] = f2bf((v1.y-mu)*rs*gb.y + bb.y);
    o8.h[6] = f2bf((v1.z-mu)*rs*gb.z + bb.z); o8.h[7] = f2bf((v1.w-mu)*rs*gb.w + bb.w);
    *(u32x4*)(n1 + (size_t)row * EMB + lane * 8) = o8.v;
  }
}

// x2 = x + (u0+u1)/(l0+l1) (not materialized; fixup recomputes); n2 = LN(x2); out = x2+b2
__global__ __launch_bounds__(256) void k_ln2(const float* __restrict__ x,
    const u16* __restrict__ att0, const u16* __restrict__ att1,
    const float* __restrict__ l0, const float* __restrict__ l1,
    const float* __restrict__ g, const float* __restrict__ b,
    const float* __restrict__ b2, u16* __restrict__ n2,
    float* __restrict__ out) {
  int wid = threadIdx.x >> 6, lane = threadIdx.x & 63;
  int row = blockIdx.x * 4 + wid;
  size_t base = (size_t)row * EMB + lane * 8;
  int mm = row >> 11, qq = row & 2047, head = lane >> 3;   // lane's 8 cols in one head
  size_t li = (size_t)(mm * 8 + head) * SEQ + qq;
  float rl = 1.0f / (l0[li] + l1[li]);
  u32x4 a0 = *(const u32x4*)(att0 + base);
  u32x4 a1 = *(const u32x4*)(att1 + base);
  f32x4 t0, t1;
  t0.x = (bflo(a0.x) + bflo(a1.x)) * rl; t0.y = (bfhi(a0.x) + bfhi(a1.x)) * rl;
  t0.z = (bflo(a0.y) + bflo(a1.y)) * rl; t0.w = (bfhi(a0.y) + bfhi(a1.y)) * rl;
  t1.x = (bflo(a0.z) + bflo(a1.z)) * rl; t1.y = (bfhi(a0.z) + bfhi(a1.z)) * rl;
  t1.z = (bflo(a0.w) + bflo(a1.w)) * rl; t1.w = (bfhi(a0.w) + bfhi(a1.w)) * rl;
  f32x4 v0 = *(const f32x4*)(x + base)     + t0;
  f32x4 v1 = *(const f32x4*)(x + base + 4) + t1;
  *(f32x4*)(out + base)     = v0 + *(const f32x4*)(b2 + lane*8);
  *(f32x4*)(out + base + 4) = v1 + *(const f32x4*)(b2 + lane*8 + 4);
  float s = v0.x+v0.y+v0.z+v0.w + v1.x+v1.y+v1.z+v1.w;
  float q = v0.x*v0.x+v0.y*v0.y+v0.z*v0.z+v0.w*v0.w
          + v1.x*v1.x+v1.y*v1.y+v1.z*v1.z+v1.w*v1.w;
  #pragma unroll
  for (int o = 1; o < 64; o <<= 1) { s += __shfl_xor(s, o); q += __shfl_xor(q, o); }
  float mu = s * (1.0f/512.0f);
  float rs = 1.0f / sqrtf(q * (1.0f/512.0f) - mu*mu + 1e-5f);
  f32x4 ga = *(const f32x4*)(g + lane*8), gb = *(const f32x4*)(g + lane*8 + 4);
  f32x4 ba = *(const f32x4*)(b + lane*8), bb = *(const f32x4*)(b + lane*8 + 4);
  union { u16 h[8]; u32x4 v; } o8;
  o8.h[0] = f2bf((v0.x-mu)*rs*ga.x + ba.x); o8.h[1] = f2bf((v0.y-mu)*rs*ga.y + ba.y);
  o8.h[2] = f2bf((v0.z-mu)*rs*ga.z + ba.z); o8.h[3] = f2bf((v0.w-mu)*rs*ga.w + ba.w);
  o8.h[4] = f2bf((v1.x-mu)*rs*gb.x + bb.x); o8.h[5] = f2bf((v1.y-mu)*rs*gb.y + bb.y);
  o8.h[6] = f2bf((v1.z-mu)*rs*gb.z + bb.z); o8.h[7] = f2bf((v1.w-mu)*rs*gb.w + bb.w);
  *(u32x4*)(n2 + (size_t)row * EMB + lane * 8) = o8.v;
}

// -------- GEMM core (r6-proven): 32KB dbuf, 1 barrier/tile, ~5 blocks/CU --------
#define GEMM_CORE(A_, Bt_, m0_, n0_)                                           \
  __shared__ u16 As[2][128 * 32];                                              \
  __shared__ u16 Bs[2][128 * 32];                                              \
  int tid = threadIdx.x;                                                       \
  int wid = tid >> 6, lane = tid & 63;                                         \
  int quad = lane >> 4, ln15 = lane & 15;                                      \
  int wm = (wid >> 1) * 64, wn = (wid & 1) * 64;                               \
  int arow = lane >> 2, acol = (lane & 3) * 8;                                 \
  const u16* gA0 = A_  + (size_t)(m0_ + wid * 32 + arow) * 512 + acol;         \
  const u16* gA1 = gA0 + (size_t)16 * 512;                                     \
  const u16* gB0 = Bt_ + (size_t)(n0_ + wid * 32 + arow) * 512 + acol;         \
  const u16* gB1 = gB0 + (size_t)16 * 512;                                     \
  f32x4 acc[4][4] = {};                                                        \
  gld16(gA0, &As[0][(wid * 32) * 32]); gld16(gA1, &As[0][(wid * 32 + 16) * 32]);\
  gld16(gB0, &Bs[0][(wid * 32) * 32]); gld16(gB1, &Bs[0][(wid * 32 + 16) * 32]);\
  for (int kt = 0; kt < 16; kt++) {                                            \
    int cur = kt & 1;                                                          \
    __syncthreads();                                                           \
    if (kt < 15) {                                                             \
      int ko = (kt + 1) * 32;                                                  \
      gld16(gA0 + ko, &As[cur ^ 1][(wid * 32) * 32]);                          \
      gld16(gA1 + ko, &As[cur ^ 1][(wid * 32 + 16) * 32]);                     \
      gld16(gB0 + ko, &Bs[cur ^ 1][(wid * 32) * 32]);                          \
      gld16(gB1 + ko, &Bs[cur ^ 1][(wid * 32 + 16) * 32]);                     \
    }                                                                          \
    bf16x8 af[4], bf[4];                                                       \
    _Pragma("unroll")                                                          \
    for (int i = 0; i < 4; i++) {                                              \
      af[i] = *(const bf16x8*)&As[cur][(wm + i * 16 + ln15) * 32 + quad * 8];  \
      bf[i] = *(const bf16x8*)&Bs[cur][(wn + i * 16 + ln15) * 32 + quad * 8];  \
    }                                                                          \
    _Pragma("unroll")                                                          \
    for (int i = 0; i < 4; i++)                                                \
      _Pragma("unroll")                                                        \
      for (int j = 0; j < 4; j++)                                              \
        acc[i][j] = __builtin_amdgcn_mfma_f32_16x16x32_bf16(af[i], bf[j],      \
                                                            acc[i][j], 0, 0, 0);\
  }                                                                            \
  __syncthreads();

// QKV: A=n1 [8192][512], Bt=wqkvT [1536][512]; scatter to Q/K [mh][s][d], Vt [mh][d][s]
// XCD swizzle (T1, r5-proven); K bias scaled by LOG2E.
__global__ __launch_bounds__(256) void k_gemm_qkv(
    const u16* __restrict__ A, const u16* __restrict__ Bt,
    const float* __restrict__ bq, const float* __restrict__ bk, const float* __restrict__ bv,
    u16* __restrict__ Qb, u16* __restrict__ Kb, u16* __restrict__ Vtb) {
  int bid = blockIdx.x + 12 * blockIdx.y;          // dispatch id, 0..767
  int c = bid & 7, r = bid >> 3;                   // XCD c, 96 blocks each
  int m0 = (c * 8 + r / 12) * 128, n0 = (r % 12) * 128;
  GEMM_CORE(A, Bt, m0, n0)
  #pragma unroll
  for (int j = 0; j < 4; j++) {
    int n = n0 + wn + j * 16 + ln15;          // uniform t within 16-lane group
    int t = n >> 9, cc = n & 511, head = cc >> 6, dd = cc & 63;
    float bias = (t == 0) ? bq[cc] : ((t == 1) ? bk[cc] * LOG2E : bv[cc]);
    #pragma unroll
    for (int i = 0; i < 4; i++) {
      int row0 = m0 + wm + i * 16 + quad * 4;
      int mm = row0 >> 11, ss0 = row0 & 2047;
      if (t == 2) {
        union { u16 h[4]; u32x2 v; } pk;
        #pragma unroll
        for (int r2 = 0; r2 < 4; r2++) pk.h[r2] = f2bf(acc[i][j][r2] + bias);
        *(u32x2*)(Vtb + ((size_t)(mm * 8 + head) * 64 + dd) * 2048 + ss0) = pk.v;
      } else {
        u16* dst = (t == 0) ? Qb : Kb;
        #pragma unroll
        for (int r2 = 0; r2 < 4; r2++)
          dst[((size_t)(mm * 8 + head) * 2048 + ss0 + r2) * 64 + dd] =
              f2bf(acc[i][j][r2] + bias);
      }
    }
  }
}

// FFN1: A=n2 [8192][512], Bt=w1T [2048][512]; spike/candidate lists only
__global__ __launch_bounds__(256) void k_gemm_ffn1(
    const u16* __restrict__ A, const u16* __restrict__ Bt, const float* __restrict__ b1,
    int* __restrict__ cnt, unsigned* __restrict__ spikeL, unsigned* __restrict__ candL) {
  int bid = blockIdx.x + 16 * blockIdx.y;          // dispatch id, 0..1023
  int c = bid & 7, r = bid >> 3;                   // XCD c, 128 blocks each
  int m0 = (c * 8 + r / 16) * 128, n0 = (r % 16) * 128;
  GEMM_CORE(A, Bt, m0, n0)
  #pragma unroll
  for (int j = 0; j < 4; j++) {
    int n = n0 + wn + j * 16 + ln15;
    float bias = b1[n];
    #pragma unroll
    for (int i = 0; i < 4; i++) {
      #pragma unroll
      for (int r2 = 0; r2 < 4; r2++) {
        int row = m0 + wm + i * 16 + quad * 4 + r2;
        float hv = acc[i][j][r2] + bias;
        if (hv >= 2.0f - MARGIN) {
          if (hv >= 2.0f + MARGIN) {
            int ix = atomicAdd(&cnt[0], 1);
            if (ix < CAP) spikeL[ix] = (unsigned)(row * 2048 + n);
          } else {
            int ix = atomicAdd(&cnt[1], 1);
            if (ix < CAP) candL[ix] = (unsigned)(row * 2048 + n);
          }
        }
      }
    }
  }
}

// ------- flash v17: v16 kv-split (proven: 42.3us, occ 30%) + relaxed launch_bounds ----
// v16's (256,4) forced VGPR to 64 -- tighter than needed: residency is GRID-capped
// at 4 blocks/CU (1024/256), and any VGPR <=128 still allows >=4 blocks. (256,3)
// gives the allocator ~85 VGPR (less VALU repack/remat on the softmax) with
// provably unchanged residency. Each kvh block plain-stores its unnormalized
// U-half (bf16 att0/att1) + l-half (f32 l0/l1); ln2/fixup combine (u0+u1)/(l0+l1).
#define F_STAGE(BUF, T0)                                                       \
  do {                                                                         \
    gld16(gK0 + (size_t)(T0) * 4096, &L.SB[BUF][0][rb0 * 64]);                 \
    gld16(gK1 + (size_t)(T0) * 4096, &L.SB[BUF][0][rb1 * 64]);                 \
    gld16(gV0 + (T0) * 64, &L.SB[BUF][1][rb0 * 64]);                           \
    gld16(gV1 + (T0) * 64, &L.SB[BUF][1][rb1 * 64]);                           \
  } while (0)

#define F_INNER(BUF)                                                           \
  do {                                                                         \
    const u16* Kc = L.SB[BUF][0];                                              \
    const u16* Vc = L.SB[BUF][1];                                              \
    f32x4 s4[2][4];                                                            \
    __builtin_amdgcn_s_setprio(1);                                             \
    _Pragma("unroll")                                                          \
    for (int j = 0; j < 4; j++) {                                              \
      bf16x8 a = *(const bf16x8*)(Kc + (j * 16 + ln15) * 64 + ((quad ^ lm) * 8)); \
      s4[0][j] = __builtin_amdgcn_mfma_f32_16x16x32_bf16(a, aQ[0][0].v, e4, 0, 0, 0); \
      s4[1][j] = __builtin_amdgcn_mfma_f32_16x16x32_bf16(a, aQ[1][0].v, e4, 0, 0, 0); \
    }                                                                          \
    _Pragma("unroll")                                                          \
    for (int j = 0; j < 4; j++) {                                              \
      bf16x8 a = *(const bf16x8*)(Kc + (j * 16 + ln15) * 64 + (((4 + quad) ^ lm) * 8)); \
      s4[0][j] = __builtin_amdgcn_mfma_f32_16x16x32_bf16(a, aQ[0][1].v, s4[0][j], 0, 0, 0); \
      s4[1][j] = __builtin_amdgcn_mfma_f32_16x16x32_bf16(a, aQ[1][1].v, s4[1][j], 0, 0, 0); \
    }                                                                          \
    __builtin_amdgcn_s_setprio(0);                                             \
    Frag4 bP[2][2];                                                            \
    _Pragma("unroll")                                                          \
    for (int h = 0; h < 2; h++) {                                              \
      unsigned pr[4][4];                                                       \
      _Pragma("unroll")                                                        \
      for (int j = 0; j < 4; j++)                                              \
        _Pragma("unroll")                                                      \
        for (int r = 0; r < 4; r++) {                                          \
          float p = __builtin_amdgcn_exp2f(s4[h][j][r]);                       \
          union { float f; unsigned u; } cc; cc.f = p;                         \
          pr[j][r] = cc.u;                                                     \
        }                                                                      \
      _Pragma("unroll")                                                        \
      for (int t = 0; t < 2; t++) {                                            \
        bP[h][t].u[0] = __builtin_amdgcn_perm(pr[2*t][1],   pr[2*t][0],   0x07060302u); \
        bP[h][t].u[1] = __builtin_amdgcn_perm(pr[2*t][3],   pr[2*t][2],   0x07060302u); \
        bP[h][t].u[2] = __builtin_amdgcn_perm(pr[2*t+1][1], pr[2*t+1][0], 0x07060302u); \
        bP[h][t].u[3] = __builtin_amdgcn_perm(pr[2*t+1][3], pr[2*t+1][2], 0x07060302u); \
      }                                                                        \
    }                                                                          \
    __builtin_amdgcn_s_setprio(1);                                             \
    lacc[0] = __builtin_amdgcn_mfma_f32_16x16x32_bf16(vOne.v, bP[0][0].v, lacc[0], 0, 0, 0); \
    lacc[1] = __builtin_amdgcn_mfma_f32_16x16x32_bf16(vOne.v, bP[1][0].v, lacc[1], 0, 0, 0); \
    lacc[0] = __builtin_amdgcn_mfma_f32_16x16x32_bf16(vOne.v, bP[0][1].v, lacc[0], 0, 0, 0); \
    lacc[1] = __builtin_amdgcn_mfma_f32_16x16x32_bf16(vOne.v, bP[1][1].v, lacc[1], 0, 0, 0); \
    _Pragma("unroll")                                                          \
    for (int t = 0; t < 2; t++)                                                \
      _Pragma("unroll")                                                        \
      for (int j = 0; j < 4; j++) {                                            \
        int row = j * 16 + ln15;                                               \
        int c0 = 4 * t + (quad >> 1), sub = (quad & 1) * 4;                    \
        Frag aV;                                                               \
        aV.u[0] = *(const u32x2*)(Vc + row * 64 + ((c0 ^ lm) * 8) + sub);      \
        aV.u[1] = *(const u32x2*)(Vc + row * 64 + (((c0 + 2) ^ lm) * 8) + sub);\
        U[0][j] = __builtin_amdgcn_mfma_f32_16x16x32_bf16(aV.v, bP[0][t].v,    \
                                                          U[0][j], 0, 0, 0);   \
        U[1][j] = __builtin_amdgcn_mfma_f32_16x16x32_bf16(aV.v, bP[1][t].v,    \
                                                          U[1][j], 0, 0, 0);   \
      }                                                                        \
    __builtin_amdgcn_s_setprio(0);                                             \
  } while (0)

__global__ __launch_bounds__(256, 3) void k_flash(
    const u16* __restrict__ Q, const u16* __restrict__ K,
    const u16* __restrict__ Vt, u16* __restrict__ att0, u16* __restrict__ att1,
    float* __restrict__ l0, float* __restrict__ l1) {
  __shared__ union {
    u16 SB[2][2][64 * 64];   // [buf][K/V][64 rows][64 u16 chunk-swizzled] 32 KB
    float T[4][16 * 68];     // per-wave epilogue transpose (after final barrier)
  } L;
  int tid = threadIdx.x, wid = tid >> 6, lane = tid & 63;
  int quad = lane >> 4, ln15 = lane & 15, lm = ln15 & 7;
  // bijective XCD swizzle: XCD c owns swz [c*128,(c+1)*128) = 4 complete
  // (head,mm) groups (16 qb x 2 kv-halves each) -> K/V + att rows L2-local.
  int bid = blockIdx.x + 32 * (blockIdx.y + 8 * (int)blockIdx.z);
  int swz = (bid & 7) * 128 + (bid >> 3);
  int kvh = swz & 1, qb = (swz >> 1) & 15, head = (swz >> 5) & 7, mm = swz >> 8;
  int mh = mm * 8 + head;
  const u16* Qp = Q  + (size_t)mh * SEQ * HD;
  const u16* Kp = K  + (size_t)mh * SEQ * HD + (size_t)kvh * 1024 * HD;
  const u16* Vp = Vt + (size_t)mh * HD * SEQ + kvh * 1024;
  u16*  attH = kvh ? att1 : att0;
  float* lH  = kvh ? l1 : l0;
  int q0 = qb * 128 + wid * 32;

  Frag aQ[2][2];   // [q-half][t]: B-operand Q[q=ln15][d=t*32+quad*8+..]
  #pragma unroll
  for (int h = 0; h < 2; h++)
    #pragma unroll
    for (int t = 0; t < 2; t++) {
      u32x4 g = *(const u32x4*)(Qp + (size_t)(q0 + h * 16 + ln15) * 64 + t * 32 + quad * 8);
      aQ[h][t].u[0].x = g.x; aQ[h][t].u[0].y = g.y;
      aQ[h][t].u[1].x = g.z; aQ[h][t].u[1].y = g.w;
    }
  const f32x4 e4 = {EXPB, EXPB, EXPB, EXPB};   // QK C-init: s4 = K~.Q + EXPB
  Frag4 vOne;      // bf16 1.0 x8 (A-operand for l-sum MFMA)
  vOne.u[0] = 0x3F803F80u; vOne.u[1] = 0x3F803F80u;
  vOne.u[2] = 0x3F803F80u; vOne.u[3] = 0x3F803F80u;

  // staging: lane -> (row l>>3, phys chunk l&7) holds global chunk (l&7)^(l>>3&7)
  int srow = lane >> 3;
  int sch  = (lane & 7) ^ (srow & 7);
  int rb0 = wid * 16, rb1 = wid * 16 + 8;
  const u16* gK0 = Kp + (size_t)(rb0 + srow) * 64 + sch * 8;
  const u16* gK1 = Kp + (size_t)(rb1 + srow) * 64 + sch * 8;
  const u16* gV0 = Vp + (size_t)(rb0 + srow) * SEQ + sch * 8;
  const u16* gV1 = Vp + (size_t)(rb1 + srow) * SEQ + sch * 8;

  f32x4 lacc[2] = {};          // [q-half]: every reg/row = sum_k P[k][q=ln15]
  f32x4 U[2][4] = {};          // [q-half][j]: U^T[d=j*16+quad*4+r][q=ln15]

  F_STAGE(0, 0);
  for (int s = 0; s < 16; s++) {
    __syncthreads();
    if (s < 15) F_STAGE((s & 1) ^ 1, s + 1);
    F_INNER(s & 1);
  }
  __syncthreads();   // protect T-union from other waves' last-step LDS reads

  #pragma unroll
  for (int h = 0; h < 2; h++) {
    if (quad == 0)
      lH[(size_t)mh * SEQ + q0 + h * 16 + ln15] = lacc[h][0];
    float* Tw = L.T[wid];
    #pragma unroll
    for (int j = 0; j < 4; j++)
      *(f32x4*)(Tw + ln15 * 68 + j * 16 + quad * 4) = U[h][j];
    #pragma unroll
    for (int s2 = 0; s2 < 4; s2++) {
      f32x4 o = *(const f32x4*)(Tw + (quad * 4 + s2) * 68 + ln15 * 4);
      union { u16 h4[4]; u32x2 v; } pk;
      pk.h4[0] = f2bf(o.x); pk.h4[1] = f2bf(o.y);
      pk.h4[2] = f2bf(o.z); pk.h4[3] = f2bf(o.w);
      *(u32x2*)(attH + ((size_t)mm * SEQ + q0 + h * 16 + quad * 4 + s2) * EMB +
                head * 64 + ln15 * 4) = pk.v;
    }
  }
}

// exact fp32 recompute of borderline h1 entries; append true spikes.
// x2 reconstructed as x + (u0+u1)/(l0+l1) -- same op sequence as k_ln2.
__global__ __launch_bounds__(256) void k_fixup(
    const float* __restrict__ x, const u16* __restrict__ att0,
    const u16* __restrict__ att1,
    const float* __restrict__ l0, const float* __restrict__ l1,
    const float* __restrict__ w1, const float* __restrict__ b1,
    const float* __restrict__ g2, const float* __restrict__ be2,
    int* __restrict__ cnt, unsigned* __restrict__ spikeL, const unsigned* __restrict__ candL) {
  __shared__ float sb[8];
  int tid = threadIdx.x;
  int nC = cnt[1]; if (nC > CAP) nC = CAP;
  for (int e = blockIdx.x; e < nC; e += gridDim.x) {
    unsigned v = candL[e];
    int row = (int)(v >> 11), col = (int)(v & 2047u);
    int mm = row >> 11, qq = row & 2047;
    const float* xr = x + (size_t)row * 512;
    const u16* a0r = att0 + (size_t)row * 512;
    const u16* a1r = att1 + (size_t)row * 512;
    size_t li0 = (size_t)(mm * 8 + (tid >> 6)) * SEQ + qq;
    size_t li1 = (size_t)(mm * 8 + ((tid + 256) >> 6)) * SEQ + qq;
    float rl0 = 1.0f / (l0[li0] + l1[li0]);
    float rl1 = 1.0f / (l0[li1] + l1[li1]);
    float x0 = xr[tid] + (b2f(a0r[tid]) + b2f(a1r[tid])) * rl0;
    float x1 = xr[tid + 256] + (b2f(a0r[tid + 256]) + b2f(a1r[tid + 256])) * rl1;
    float s = x0 + x1, q = x0 * x0 + x1 * x1;
    #pragma unroll
    for (int o = 1; o < 64; o <<= 1) { s += __shfl_xor(s, o); q += __shfl_xor(q, o); }
    if ((tid & 63) == 0) { sb[tid >> 6] = s; sb[4 + (tid >> 6)] = q; }
    __syncthreads();
    float st = sb[0] + sb[1] + sb[2] + sb[3];
    float qt = sb[4] + sb[5] + sb[6] + sb[7];
    __syncthreads();
    float mu = st * (1.f / 512.f);
    float rs = 1.f / sqrtf(qt * (1.f / 512.f) - mu * mu + 1e-5f);
    float na = (x0 - mu) * rs * g2[tid] + be2[tid];
    float nb = (x1 - mu) * rs * g2[tid + 256] + be2[tid + 256];
    float dd = na * w1[(size_t)tid * 2048 + col] + nb * w1[(size_t)(tid + 256) * 2048 + col];
    #pragma unroll
    for (int o = 1; o < 64; o <<= 1) dd += __shfl_xor(dd, o);
    if ((tid & 63) == 0) sb[tid >> 6] = dd;
    __syncthreads();
    if (tid == 0) {
      float hv = sb[0] + sb[1] + sb[2] + sb[3] + b1[col];
      if (hv >= 2.0f) { int ix = atomicAdd(&cnt[0], 1); if (ix < CAP) spikeL[ix] = v; }
    }
    __syncthreads();
  }
}

// out[row,:] += w2[col,:] for each spike
__global__ void k_apply(const float* __restrict__ w2, const int* __restrict__ cnt,
                        const unsigned* __restrict__ spikeL, float* __restrict__ out) {
  int n = cnt[0]; if (n > CAP) n = CAP;
  int tid = threadIdx.x;
  for (int e = blockIdx.x; e < n; e += gridDim.x) {
    unsigned v = spikeL[e];
    int row = (int)(v >> 11), col = (int)(v & 2047u);
    atomicAdd(&out[(size_t)row * 512 + tid * 2 + 0], w2[(size_t)col * 512 + tid * 2 + 0]);
    atomicAdd(&out[(size_t)row * 512 + tid * 2 + 1], w2[(size_t)col * 512 + tid * 2 + 1]);
  }
}

// ---------------- launch ----------------

extern "C" void kernel_launch(void* const* d_in, const int* in_sizes, int n_in,
                              void* d_out, int out_size, void* d_ws, size_t ws_size,
                              hipStream_t stream) {
  (void)in_sizes; (void)n_in; (void)out_size; (void)ws_size;
  const float* x   = (const float*)d_in[0];
  const float* wq  = (const float*)d_in[1];
  const float* bq  = (const float*)d_in[2];
  const float* wk  = (const float*)d_in[3];
  const float* bk  = (const float*)d_in[4];
  const float* wv  = (const float*)d_in[5];
  const float* bv  = (const float*)d_in[6];
  const float* w1  = (const float*)d_in[7];
  const float* b1  = (const float*)d_in[8];
  const float* w2  = (const float*)d_in[9];
  const float* b2  = (const float*)d_in[10];
  const float* g1  = (const float*)d_in[11];
  const float* be1 = (const float*)d_in[12];
  const float* g2  = (const float*)d_in[13];
  const float* be2 = (const float*)d_in[14];
  float* out = (float*)d_out;

  char* w = (char*)d_ws;
  size_t off = 0;
  auto take = [&](size_t bytes) { char* p = w + off; off += (bytes + 255) & ~(size_t)255; return p; };
  int*      cnt    = (int*)take(256);
  u16*      n1     = (u16*)take((size_t)ROWS * EMB * 2);
  u16*      wqkvT  = (u16*)take((size_t)1536 * 512 * 2);
  u16*      w1T    = (u16*)take((size_t)2048 * 512 * 2);
  u16*      Qb     = (u16*)take((size_t)MB * NH * SEQ * HD * 2);
  u16*      Kb     = (u16*)take((size_t)MB * NH * SEQ * HD * 2);
  u16*      Vtb    = (u16*)take((size_t)MB * NH * SEQ * HD * 2);
  u16*      att0   = (u16*)take((size_t)ROWS * EMB * 2);          // U half 0 (bf16)
  u16*      att1   = (u16*)take((size_t)ROWS * EMB * 2);          // U half 1 (bf16)
  float*    l0     = (float*)take((size_t)MB * NH * SEQ * 4);     // l half 0
  float*    l1     = (float*)take((size_t)MB * NH * SEQ * 4);     // l half 1
  u16*      n2     = (u16*)take((size_t)ROWS * EMB * 2);
  unsigned* spikeL = (unsigned*)take((size_t)CAP * 4);
  unsigned* candL  = (unsigned*)take((size_t)CAP * 4);

  k_prep<<<3840, 256, 0, stream>>>(x, g1, be1, wq, wk, wv, w1, n1, wqkvT, w1T, cnt);
  k_gemm_qkv<<<dim3(12, 64), 256, 0, stream>>>(n1, wqkvT, bq, bk, bv, Qb, Kb, Vtb);
  k_flash<<<dim3(32, 8, 4), 256, 0, stream>>>(Qb, Kb, Vtb, att0, att1, l0, l1);
  k_ln2<<<ROWS / 4, 256, 0, stream>>>(x, att0, att1, l0, l1, g2, be2, b2, n2, out);
  k_gemm_ffn1<<<dim3(16, 64), 256, 0, stream>>>(n2, w1T, b1, cnt, spikeL, candL);
  k_fixup<<<256, 256, 0, stream>>>(x, att0, att1, l0, l1, w1, b1, g2, be2, cnt, spikeL, candL);
  k_apply<<<128, 256, 0, stream>>>(w2, cnt, spikeL, out);
}

// Round 12
// 194.761 us; speedup vs baseline: 1.0568x; 1.0553x over previous
//
#include <hip/hip_runtime.h>
#include <stdint.h>

#define EMB 512
#define SEQ 2048
#define MB 4
#define NH 8
#define HD 64
#define ROWS (MB*SEQ)          // 8192
#define MARGIN 0.02f
#define CAP 65536
#define LOG2E 1.44269504f
#define EXPB (-17.3123405f)    // -12 * log2(e)

typedef unsigned short u16;
typedef __attribute__((ext_vector_type(8))) short bf16x8;   // 8 bf16 (4 VGPRs)
typedef __attribute__((ext_vector_type(4))) float f32x4;
typedef __attribute__((ext_vector_type(2))) unsigned int u32x2;
typedef __attribute__((ext_vector_type(4))) unsigned int u32x4;

union Frag { u32x2 u[2]; bf16x8 v; };
union Frag4 { unsigned u[4]; bf16x8 v; };

__device__ __forceinline__ u16 f2bf(float f) {
  union { float f; unsigned u; } a; a.f = f;
  unsigned r = a.u + 0x7FFFu + ((a.u >> 16) & 1u);  // RNE
  return (u16)(r >> 16);
}
__device__ __forceinline__ float bflo(unsigned u) {
  union { unsigned u; float f; } c; c.u = u << 16; return c.f;
}
__device__ __forceinline__ float bfhi(unsigned u) {
  union { unsigned u; float f; } c; c.u = u & 0xffff0000u; return c.f;
}
__device__ __forceinline__ float b2f(u16 h) {
  union { unsigned u; float f; } c; c.u = (unsigned)h << 16; return c.f;
}
// async global->LDS, 16B per lane; LDS dest = wave-uniform base + lane*16
__device__ __forceinline__ void gld16(const void* g, void* l) {
  __builtin_amdgcn_global_load_lds(
      (const __attribute__((address_space(1))) void*)g,
      (__attribute__((address_space(3))) void*)l, 16, 0, 0);
}

// ---------------- fused prep: 4 weight transposes (blocks 0..1791) + LN1 (1792..3839) ----
// wk is pre-scaled by LOG2E (flash folds softmax's s*LOG2E into K itself;
// scaling happens BEFORE bf16 rounding -> same relative rounding error).

__global__ __launch_bounds__(256) void k_prep(
    const float* __restrict__ x, const float* __restrict__ g1, const float* __restrict__ be1,
    const float* __restrict__ wq, const float* __restrict__ wk,
    const float* __restrict__ wv, const float* __restrict__ w1,
    u16* __restrict__ n1, u16* __restrict__ wqkvT, u16* __restrict__ w1T,
    int* __restrict__ cnt) {
  __shared__ float tile[32][33];
  int b = blockIdx.x, tid = threadIdx.x;
  if (b < 1792) {
    const float* src; u16* dst; int N, bx, by;
    float scl = 1.0f;
    if (b < 768) {
      int z = b >> 8, rem = b & 255; bx = rem & 15; by = rem >> 4; N = 512;
      src = (z == 0) ? wq : ((z == 1) ? wk : wv);
      if (z == 1) scl = LOG2E;
      dst = wqkvT + z * 512 * 512;
    } else {
      int rem = b - 768; bx = rem & 63; by = rem >> 6; N = 2048;
      src = w1; dst = w1T;
    }
    int tx = tid & 31, ty = tid >> 5;
    int k0 = by * 32, n0 = bx * 32;
    for (int i = 0; i < 32; i += 8)
      tile[ty + i][tx] = src[(size_t)(k0 + ty + i) * N + n0 + tx];
    __syncthreads();
    for (int i = 0; i < 32; i += 8)
      dst[(size_t)(n0 + ty + i) * 512 + k0 + tx] = f2bf(tile[tx][ty + i] * scl);
  } else {
    if (b == 1792 && tid < 2) cnt[tid] = 0;
    int wid = tid >> 6, lane = tid & 63;
    int row = (b - 1792) * 4 + wid;
    const float* xr = x + (size_t)row * EMB + lane * 8;
    f32x4 v0 = *(const f32x4*)xr;
    f32x4 v1 = *(const f32x4*)(xr + 4);
    float s = v0.x+v0.y+v0.z+v0.w + v1.x+v1.y+v1.z+v1.w;
    float q = v0.x*v0.x+v0.y*v0.y+v0.z*v0.z+v0.w*v0.w
            + v1.x*v1.x+v1.y*v1.y+v1.z*v1.z+v1.w*v1.w;
    #pragma unroll
    for (int o = 1; o < 64; o <<= 1) { s += __shfl_xor(s, o); q += __shfl_xor(q, o); }
    float mu = s * (1.0f/512.0f);
    float rs = 1.0f / sqrtf(q * (1.0f/512.0f) - mu*mu + 1e-5f);
    f32x4 ga = *(const f32x4*)(g1 + lane*8), gb = *(const f32x4*)(g1 + lane*8 + 4);
    f32x4 ba = *(const f32x4*)(be1 + lane*8), bb = *(const f32x4*)(be1 + lane*8 + 4);
    union { u16 h[8]; u32x4 v; } o8;
    o8.h[0] = f2bf((v0.x-mu)*rs*ga.x + ba.x); o8.h[1] = f2bf((v0.y-mu)*rs*ga.y + ba.y);
    o8.h[2] = f2bf((v0.z-mu)*rs*ga.z + ba.z); o8.h[3] = f2bf((v0.w-mu)*rs*ga.w + ba.w);
    o8.h[4] = f2bf((v1.x-mu)*rs*gb.x + bb.x); o8.h[5] = f2bf((v1.y-mu)*rs*gb.y + bb.y);
    o8.h[6] = f2bf((v1.z-mu)*rs*gb.z + bb.z); o8.h[7] = f2bf((v1.w-mu)*rs*gb.w + bb.w);
    *(u32x4*)(n1 + (size_t)row * EMB + lane * 8) = o8.v;
  }
}

// x2 = x + att(bf16) (not materialized; fixup recomputes); n2 = LN(x2); out = x2 + b2
__global__ __launch_bounds__(256) void k_ln2(const float* __restrict__ x,
    const u16* __restrict__ att, const float* __restrict__ g, const float* __restrict__ b,
    const float* __restrict__ b2, u16* __restrict__ n2,
    float* __restrict__ out) {
  int wid = threadIdx.x >> 6, lane = threadIdx.x & 63;
  int row = blockIdx.x * 4 + wid;
  size_t base = (size_t)row * EMB + lane * 8;
  u32x4 av = *(const u32x4*)(att + base);
  f32x4 t0, t1;
  t0.x = bflo(av.x); t0.y = bfhi(av.x); t0.z = bflo(av.y); t0.w = bfhi(av.y);
  t1.x = bflo(av.z); t1.y = bfhi(av.z); t1.z = bflo(av.w); t1.w = bfhi(av.w);
  f32x4 v0 = *(const f32x4*)(x + base)     + t0;
  f32x4 v1 = *(const f32x4*)(x + base + 4) + t1;
  *(f32x4*)(out + base)     = v0 + *(const f32x4*)(b2 + lane*8);
  *(f32x4*)(out + base + 4) = v1 + *(const f32x4*)(b2 + lane*8 + 4);
  float s = v0.x+v0.y+v0.z+v0.w + v1.x+v1.y+v1.z+v1.w;
  float q = v0.x*v0.x+v0.y*v0.y+v0.z*v0.z+v0.w*v0.w
          + v1.x*v1.x+v1.y*v1.y+v1.z*v1.z+v1.w*v1.w;
  #pragma unroll
  for (int o = 1; o < 64; o <<= 1) { s += __shfl_xor(s, o); q += __shfl_xor(q, o); }
  float mu = s * (1.0f/512.0f);
  float rs = 1.0f / sqrtf(q * (1.0f/512.0f) - mu*mu + 1e-5f);
  f32x4 ga = *(const f32x4*)(g + lane*8), gb = *(const f32x4*)(g + lane*8 + 4);
  f32x4 ba = *(const f32x4*)(b + lane*8), bb = *(const f32x4*)(b + lane*8 + 4);
  union { u16 h[8]; u32x4 v; } o8;
  o8.h[0] = f2bf((v0.x-mu)*rs*ga.x + ba.x); o8.h[1] = f2bf((v0.y-mu)*rs*ga.y + ba.y);
  o8.h[2] = f2bf((v0.z-mu)*rs*ga.z + ba.z); o8.h[3] = f2bf((v0.w-mu)*rs*ga.w + ba.w);
  o8.h[4] = f2bf((v1.x-mu)*rs*gb.x + bb.x); o8.h[5] = f2bf((v1.y-mu)*rs*gb.y + bb.y);
  o8.h[6] = f2bf((v1.z-mu)*rs*gb.z + bb.z); o8.h[7] = f2bf((v1.w-mu)*rs*gb.w + bb.w);
  *(u32x4*)(n2 + (size_t)row * EMB + lane * 8) = o8.v;
}

// -------- GEMM core (r6-proven): 32KB dbuf, 1 barrier/tile, ~5 blocks/CU --------
#define GEMM_CORE(A_, Bt_, m0_, n0_)                                           \
  __shared__ u16 As[2][128 * 32];                                              \
  __shared__ u16 Bs[2][128 * 32];                                              \
  int tid = threadIdx.x;                                                       \
  int wid = tid >> 6, lane = tid & 63;                                         \
  int quad = lane >> 4, ln15 = lane & 15;                                      \
  int wm = (wid >> 1) * 64, wn = (wid & 1) * 64;                               \
  int arow = lane >> 2, acol = (lane & 3) * 8;                                 \
  const u16* gA0 = A_  + (size_t)(m0_ + wid * 32 + arow) * 512 + acol;         \
  const u16* gA1 = gA0 + (size_t)16 * 512;                                     \
  const u16* gB0 = Bt_ + (size_t)(n0_ + wid * 32 + arow) * 512 + acol;         \
  const u16* gB1 = gB0 + (size_t)16 * 512;                                     \
  f32x4 acc[4][4] = {};                                                        \
  gld16(gA0, &As[0][(wid * 32) * 32]); gld16(gA1, &As[0][(wid * 32 + 16) * 32]);\
  gld16(gB0, &Bs[0][(wid * 32) * 32]); gld16(gB1, &Bs[0][(wid * 32 + 16) * 32]);\
  for (int kt = 0; kt < 16; kt++) {                                            \
    int cur = kt & 1;                                                          \
    __syncthreads();                                                           \
    if (kt < 15) {                                                             \
      int ko = (kt + 1) * 32;                                                  \
      gld16(gA0 + ko, &As[cur ^ 1][(wid * 32) * 32]);                          \
      gld16(gA1 + ko, &As[cur ^ 1][(wid * 32 + 16) * 32]);                     \
      gld16(gB0 + ko, &Bs[cur ^ 1][(wid * 32) * 32]);                          \
      gld16(gB1 + ko, &Bs[cur ^ 1][(wid * 32 + 16) * 32]);                     \
    }                                                                          \
    bf16x8 af[4], bf[4];                                                       \
    _Pragma("unroll")                                                          \
    for (int i = 0; i < 4; i++) {                                              \
      af[i] = *(const bf16x8*)&As[cur][(wm + i * 16 + ln15) * 32 + quad * 8];  \
      bf[i] = *(const bf16x8*)&Bs[cur][(wn + i * 16 + ln15) * 32 + quad * 8];  \
    }                                                                          \
    _Pragma("unroll")                                                          \
    for (int i = 0; i < 4; i++)                                                \
      _Pragma("unroll")                                                        \
      for (int j = 0; j < 4; j++)                                              \
        acc[i][j] = __builtin_amdgcn_mfma_f32_16x16x32_bf16(af[i], bf[j],      \
                                                            acc[i][j], 0, 0, 0);\
  }                                                                            \
  __syncthreads();

// QKV: A=n1 [8192][512], Bt=wqkvT [1536][512]; scatter to Q/K [mh][s][d], Vt [mh][d][s]
// XCD swizzle (T1, r5-proven): XCD c owns m-rows [c*8, c*8+8) x all 12 n-cols.
// K bias is scaled by LOG2E (wkT already pre-scaled in k_prep).
__global__ __launch_bounds__(256) void k_gemm_qkv(
    const u16* __restrict__ A, const u16* __restrict__ Bt,
    const float* __restrict__ bq, const float* __restrict__ bk, const float* __restrict__ bv,
    u16* __restrict__ Qb, u16* __restrict__ Kb, u16* __restrict__ Vtb) {
  int bid = blockIdx.x + 12 * blockIdx.y;          // dispatch id, 0..767
  int c = bid & 7, r = bid >> 3;                   // XCD c, 96 blocks each
  int m0 = (c * 8 + r / 12) * 128, n0 = (r % 12) * 128;
  GEMM_CORE(A, Bt, m0, n0)
  #pragma unroll
  for (int j = 0; j < 4; j++) {
    int n = n0 + wn + j * 16 + ln15;          // uniform t within 16-lane group
    int t = n >> 9, cc = n & 511, head = cc >> 6, dd = cc & 63;
    float bias = (t == 0) ? bq[cc] : ((t == 1) ? bk[cc] * LOG2E : bv[cc]);
    #pragma unroll
    for (int i = 0; i < 4; i++) {
      int row0 = m0 + wm + i * 16 + quad * 4;
      int mm = row0 >> 11, ss0 = row0 & 2047;
      if (t == 2) {
        union { u16 h[4]; u32x2 v; } pk;
        #pragma unroll
        for (int r2 = 0; r2 < 4; r2++) pk.h[r2] = f2bf(acc[i][j][r2] + bias);
        *(u32x2*)(Vtb + ((size_t)(mm * 8 + head) * 64 + dd) * 2048 + ss0) = pk.v;
      } else {
        u16* dst = (t == 0) ? Qb : Kb;
        #pragma unroll
        for (int r2 = 0; r2 < 4; r2++)
          dst[((size_t)(mm * 8 + head) * 2048 + ss0 + r2) * 64 + dd] =
              f2bf(acc[i][j][r2] + bias);
      }
    }
  }
}

// FFN1: A=n2 [8192][512], Bt=w1T [2048][512]; spike/candidate lists only
// Same XCD swizzle: 1024 blocks = 8 XCDs x 128; XCD c owns m-rows [c*8, c*8+8).
__global__ __launch_bounds__(256) void k_gemm_ffn1(
    const u16* __restrict__ A, const u16* __restrict__ Bt, const float* __restrict__ b1,
    int* __restrict__ cnt, unsigned* __restrict__ spikeL, unsigned* __restrict__ candL) {
  int bid = blockIdx.x + 16 * blockIdx.y;          // dispatch id, 0..1023
  int c = bid & 7, r = bid >> 3;                   // XCD c, 128 blocks each
  int m0 = (c * 8 + r / 16) * 128, n0 = (r % 16) * 128;
  GEMM_CORE(A, Bt, m0, n0)
  #pragma unroll
  for (int j = 0; j < 4; j++) {
    int n = n0 + wn + j * 16 + ln15;
    float bias = b1[n];
    #pragma unroll
    for (int i = 0; i < 4; i++) {
      #pragma unroll
      for (int r2 = 0; r2 < 4; r2++) {
        int row = m0 + wm + i * 16 + quad * 4 + r2;
        float hv = acc[i][j][r2] + bias;
        if (hv >= 2.0f - MARGIN) {
          if (hv >= 2.0f + MARGIN) {
            int ix = atomicAdd(&cnt[0], 1);
            if (ix < CAP) spikeL[ix] = (unsigned)(row * 2048 + n);
          } else {
            int ix = atomicAdd(&cnt[1], 1);
            if (ix < CAP) candL[ix] = (unsigned)(row * 2048 + n);
          }
        }
      }
    }
  }
}

// ------- flash v13 (proven 44.2-47.1us): fmaf-free softmax, XCD swizzle, l-via-MFMA ----
// Session ledger for flash: v13 is the local optimum of this structure.
// Occupancy/ILP restructures all failed: v9/v10 (traffic doubling), v12 (spill),
// v14 (4x bank conflicts), v15 (memset/atomics correctness), v16/v17 (kv-split
// kernel win < pipeline combine tax). 32 q/wave, 2 blocks/CU, serial QK->SM->PV.
#define F_STAGE(BUF, T0)                                                       \
  do {                                                                         \
    gld16(gK0 + (size_t)(T0)       * 4096, &L.SB[BUF][0][0][rb0 * 64]);        \
    gld16(gK1 + (size_t)(T0)       * 4096, &L.SB[BUF][0][0][rb1 * 64]);        \
    gld16(gK0 + (size_t)((T0) + 1) * 4096, &L.SB[BUF][0][1][rb0 * 64]);        \
    gld16(gK1 + (size_t)((T0) + 1) * 4096, &L.SB[BUF][0][1][rb1 * 64]);        \
    gld16(gV0 + (T0) * 64,       &L.SB[BUF][1][0][rb0 * 64]);                  \
    gld16(gV1 + (T0) * 64,       &L.SB[BUF][1][0][rb1 * 64]);                  \
    gld16(gV0 + ((T0) + 1) * 64, &L.SB[BUF][1][1][rb0 * 64]);                  \
    gld16(gV1 + ((T0) + 1) * 64, &L.SB[BUF][1][1][rb1 * 64]);                  \
  } while (0)

#define F_INNER(BUF, SUB)                                                      \
  do {                                                                         \
    const u16* Kc = L.SB[BUF][0][SUB];                                         \
    const u16* Vc = L.SB[BUF][1][SUB];                                         \
    f32x4 s4[2][4];                                                            \
    __builtin_amdgcn_s_setprio(1);                                             \
    _Pragma("unroll")                                                          \
    for (int j = 0; j < 4; j++) {                                              \
      bf16x8 a = *(const bf16x8*)(Kc + (j * 16 + ln15) * 64 + ((quad ^ lm) * 8)); \
      s4[0][j] = __builtin_amdgcn_mfma_f32_16x16x32_bf16(a, aQ[0][0].v, e4, 0, 0, 0); \
      s4[1][j] = __builtin_amdgcn_mfma_f32_16x16x32_bf16(a, aQ[1][0].v, e4, 0, 0, 0); \
    }                                                                          \
    _Pragma("unroll")                                                          \
    for (int j = 0; j < 4; j++) {                                              \
      bf16x8 a = *(const bf16x8*)(Kc + (j * 16 + ln15) * 64 + (((4 + quad) ^ lm) * 8)); \
      s4[0][j] = __builtin_amdgcn_mfma_f32_16x16x32_bf16(a, aQ[0][1].v, s4[0][j], 0, 0, 0); \
      s4[1][j] = __builtin_amdgcn_mfma_f32_16x16x32_bf16(a, aQ[1][1].v, s4[1][j], 0, 0, 0); \
    }                                                                          \
    __builtin_amdgcn_s_setprio(0);                                             \
    Frag4 bP[2][2];                                                            \
    _Pragma("unroll")                                                          \
    for (int h = 0; h < 2; h++) {                                              \
      unsigned pr[4][4];                                                       \
      _Pragma("unroll")                                                        \
      for (int j = 0; j < 4; j++)                                              \
        _Pragma("unroll")                                                      \
        for (int r = 0; r < 4; r++) {                                          \
          float p = __builtin_amdgcn_exp2f(s4[h][j][r]);                       \
          union { float f; unsigned u; } cc; cc.f = p;                         \
          pr[j][r] = cc.u;                                                     \
        }                                                                      \
      _Pragma("unroll")                                                        \
      for (int t = 0; t < 2; t++) {                                            \
        bP[h][t].u[0] = __builtin_amdgcn_perm(pr[2*t][1],   pr[2*t][0],   0x07060302u); \
        bP[h][t].u[1] = __builtin_amdgcn_perm(pr[2*t][3],   pr[2*t][2],   0x07060302u); \
        bP[h][t].u[2] = __builtin_amdgcn_perm(pr[2*t+1][1], pr[2*t+1][0], 0x07060302u); \
        bP[h][t].u[3] = __builtin_amdgcn_perm(pr[2*t+1][3], pr[2*t+1][2], 0x07060302u); \
      }                                                                        \
    }                                                                          \
    __builtin_amdgcn_s_setprio(1);                                             \
    lacc[0] = __builtin_amdgcn_mfma_f32_16x16x32_bf16(vOne.v, bP[0][0].v, lacc[0], 0, 0, 0); \
    lacc[1] = __builtin_amdgcn_mfma_f32_16x16x32_bf16(vOne.v, bP[1][0].v, lacc[1], 0, 0, 0); \
    lacc[0] = __builtin_amdgcn_mfma_f32_16x16x32_bf16(vOne.v, bP[0][1].v, lacc[0], 0, 0, 0); \
    lacc[1] = __builtin_amdgcn_mfma_f32_16x16x32_bf16(vOne.v, bP[1][1].v, lacc[1], 0, 0, 0); \
    _Pragma("unroll")                                                          \
    for (int t = 0; t < 2; t++)                                                \
      _Pragma("unroll")                                                        \
      for (int j = 0; j < 4; j++) {                                            \
        int row = j * 16 + ln15;                                               \
        int c0 = 4 * t + (quad >> 1), sub = (quad & 1) * 4;                    \
        Frag aV;                                                               \
        aV.u[0] = *(const u32x2*)(Vc + row * 64 + ((c0 ^ lm) * 8) + sub);      \
        aV.u[1] = *(const u32x2*)(Vc + row * 64 + (((c0 + 2) ^ lm) * 8) + sub);\
        U[0][j] = __builtin_amdgcn_mfma_f32_16x16x32_bf16(aV.v, bP[0][t].v,    \
                                                          U[0][j], 0, 0, 0);   \
        U[1][j] = __builtin_amdgcn_mfma_f32_16x16x32_bf16(aV.v, bP[1][t].v,    \
                                                          U[1][j], 0, 0, 0);   \
      }                                                                        \
    __builtin_amdgcn_s_setprio(0);                                             \
  } while (0)

#define F_STEP(CUR, S)                                                         \
  do {                                                                         \
    __syncthreads();                                                           \
    if ((S) < 15) F_STAGE((CUR) ^ 1, 2 * (S) + 2);                             \
    F_INNER(CUR, 0);                                                           \
    F_INNER(CUR, 1);                                                           \
  } while (0)

__global__ __launch_bounds__(256, 2) void k_flash(
    const u16* __restrict__ Q, const u16* __restrict__ K,
    const u16* __restrict__ Vt, u16* __restrict__ att) {
  __shared__ union {
    u16 SB[2][2][2][64 * 64];  // [buf][K/V][sub][64 rows][64 u16 chunk-swizzled] 64 KB
    float T[4][16 * 68];       // per-wave epilogue transpose (after final barrier)
  } L;
  int tid = threadIdx.x, wid = tid >> 6, lane = tid & 63;
  int quad = lane >> 4, ln15 = lane & 15, lm = ln15 & 7;
  // bijective XCD swizzle: dispatch id -> XCD (bid&7); XCD c gets contiguous
  // swz range [c*64, c*64+64) = 4 complete (head,mm) groups (16 qb each).
  int bid = blockIdx.x + 16 * (blockIdx.y + 8 * (int)blockIdx.z);
  int swz = (bid & 7) * 64 + (bid >> 3);
  int qb = swz & 15, head = (swz >> 4) & 7, mm = swz >> 7;
  int mh = mm * 8 + head;
  const u16* Qp = Q  + (size_t)mh * SEQ * HD;
  const u16* Kp = K  + (size_t)mh * SEQ * HD;
  const u16* Vp = Vt + (size_t)mh * HD * SEQ;
  int q0 = qb * 128 + wid * 32;

  Frag aQ[2][2];   // [q-half][t]: B-operand Q[q=ln15][d=t*32+quad*8+..]
  #pragma unroll
  for (int h = 0; h < 2; h++)
    #pragma unroll
    for (int t = 0; t < 2; t++) {
      u32x4 g = *(const u32x4*)(Qp + (size_t)(q0 + h * 16 + ln15) * 64 + t * 32 + quad * 8);
      aQ[h][t].u[0].x = g.x; aQ[h][t].u[0].y = g.y;
      aQ[h][t].u[1].x = g.z; aQ[h][t].u[1].y = g.w;
    }
  const f32x4 e4 = {EXPB, EXPB, EXPB, EXPB};   // QK C-init: s4 = K~.Q + EXPB
  Frag4 vOne;      // bf16 1.0 x8 (A-operand for l-sum MFMA)
  vOne.u[0] = 0x3F803F80u; vOne.u[1] = 0x3F803F80u;
  vOne.u[2] = 0x3F803F80u; vOne.u[3] = 0x3F803F80u;

  // staging: lane -> (row l>>3, phys chunk l&7) holds global chunk (l&7)^(l>>3&7)
  int srow = lane >> 3;
  int sch  = (lane & 7) ^ (srow & 7);
  int rb0 = wid * 16, rb1 = wid * 16 + 8;
  const u16* gK0 = Kp + (size_t)(rb0 + srow) * 64 + sch * 8;
  const u16* gK1 = Kp + (size_t)(rb1 + srow) * 64 + sch * 8;
  const u16* gV0 = Vp + (size_t)(rb0 + srow) * SEQ + sch * 8;
  const u16* gV1 = Vp + (size_t)(rb1 + srow) * SEQ + sch * 8;

  f32x4 lacc[2] = {};          // [q-half]: every reg/row = sum_k P[k][q=ln15]
  f32x4 U[2][4] = {};          // [q-half][j]: U^T[d=j*16+quad*4+r][q=ln15]

  F_STAGE(0, 0);
  for (int it = 0; it < 8; it++) {
    F_STEP(0, 2 * it);
    F_STEP(1, 2 * it + 1);
  }
  __syncthreads();   // protect T-union from other waves' last-step LDS reads

  #pragma unroll
  for (int h = 0; h < 2; h++) {
    float rl = 1.0f / lacc[h][0];
    float* Tw = L.T[wid];
    #pragma unroll
    for (int j = 0; j < 4; j++)
      *(f32x4*)(Tw + ln15 * 68 + j * 16 + quad * 4) = U[h][j] * rl;
    #pragma unroll
    for (int s = 0; s < 4; s++) {
      f32x4 o = *(const f32x4*)(Tw + (quad * 4 + s) * 68 + ln15 * 4);
      union { u16 h4[4]; u32x2 v; } pk;
      pk.h4[0] = f2bf(o.x); pk.h4[1] = f2bf(o.y);
      pk.h4[2] = f2bf(o.z); pk.h4[3] = f2bf(o.w);
      *(u32x2*)(att + ((size_t)mm * SEQ + q0 + h * 16 + quad * 4 + s) * EMB +
                head * 64 + ln15 * 4) = pk.v;
    }
  }
}

// exact fp32 recompute of borderline h1 entries; append true spikes.
// x2 is reconstructed as x + bf2f(att) (bit-identical to ln2's fp32 add).
__global__ __launch_bounds__(256) void k_fixup(
    const float* __restrict__ x, const u16* __restrict__ att,
    const float* __restrict__ w1, const float* __restrict__ b1,
    const float* __restrict__ g2, const float* __restrict__ be2,
    int* __restrict__ cnt, unsigned* __restrict__ spikeL, const unsigned* __restrict__ candL) {
  __shared__ float sb[8];
  int tid = threadIdx.x;
  int nC = cnt[1]; if (nC > CAP) nC = CAP;
  for (int e = blockIdx.x; e < nC; e += gridDim.x) {
    unsigned v = candL[e];
    int row = (int)(v >> 11), col = (int)(v & 2047u);
    const float* xr = x + (size_t)row * 512;
    const u16* ar = att + (size_t)row * 512;
    float x0 = xr[tid] + b2f(ar[tid]);
    float x1 = xr[tid + 256] + b2f(ar[tid + 256]);
    float s = x0 + x1, q = x0 * x0 + x1 * x1;
    #pragma unroll
    for (int o = 1; o < 64; o <<= 1) { s += __shfl_xor(s, o); q += __shfl_xor(q, o); }
    if ((tid & 63) == 0) { sb[tid >> 6] = s; sb[4 + (tid >> 6)] = q; }
    __syncthreads();
    float st = sb[0] + sb[1] + sb[2] + sb[3];
    float qt = sb[4] + sb[5] + sb[6] + sb[7];
    __syncthreads();
    float mu = st * (1.f / 512.f);
    float rs = 1.f / sqrtf(qt * (1.f / 512.f) - mu * mu + 1e-5f);
    float na = (x0 - mu) * rs * g2[tid] + be2[tid];
    float nb = (x1 - mu) * rs * g2[tid + 256] + be2[tid + 256];
    float dd = na * w1[(size_t)tid * 2048 + col] + nb * w1[(size_t)(tid + 256) * 2048 + col];
    #pragma unroll
    for (int o = 1; o < 64; o <<= 1) dd += __shfl_xor(dd, o);
    if ((tid & 63) == 0) sb[tid >> 6] = dd;
    __syncthreads();
    if (tid == 0) {
      float hv = sb[0] + sb[1] + sb[2] + sb[3] + b1[col];
      if (hv >= 2.0f) { int ix = atomicAdd(&cnt[0], 1); if (ix < CAP) spikeL[ix] = v; }
    }
    __syncthreads();
  }
}

// out[row,:] += w2[col,:] for each spike
__global__ void k_apply(const float* __restrict__ w2, const int* __restrict__ cnt,
                        const unsigned* __restrict__ spikeL, float* __restrict__ out) {
  int n = cnt[0]; if (n > CAP) n = CAP;
  int tid = threadIdx.x;
  for (int e = blockIdx.x; e < n; e += gridDim.x) {
    unsigned v = spikeL[e];
    int row = (int)(v >> 11), col = (int)(v & 2047u);
    atomicAdd(&out[(size_t)row * 512 + tid * 2 + 0], w2[(size_t)col * 512 + tid * 2 + 0]);
    atomicAdd(&out[(size_t)row * 512 + tid * 2 + 1], w2[(size_t)col * 512 + tid * 2 + 1]);
  }
}

// ---------------- launch ----------------

extern "C" void kernel_launch(void* const* d_in, const int* in_sizes, int n_in,
                              void* d_out, int out_size, void* d_ws, size_t ws_size,
                              hipStream_t stream) {
  (void)in_sizes; (void)n_in; (void)out_size; (void)ws_size;
  const float* x   = (const float*)d_in[0];
  const float* wq  = (const float*)d_in[1];
  const float* bq  = (const float*)d_in[2];
  const float* wk  = (const float*)d_in[3];
  const float* bk  = (const float*)d_in[4];
  const float* wv  = (const float*)d_in[5];
  const float* bv  = (const float*)d_in[6];
  const float* w1  = (const float*)d_in[7];
  const float* b1  = (const float*)d_in[8];
  const float* w2  = (const float*)d_in[9];
  const float* b2  = (const float*)d_in[10];
  const float* g1  = (const float*)d_in[11];
  const float* be1 = (const float*)d_in[12];
  const float* g2  = (const float*)d_in[13];
  const float* be2 = (const float*)d_in[14];
  float* out = (float*)d_out;

  char* w = (char*)d_ws;
  size_t off = 0;
  auto take = [&](size_t bytes) { char* p = w + off; off += (bytes + 255) & ~(size_t)255; return p; };
  int*      cnt    = (int*)take(256);
  u16*      n1     = (u16*)take((size_t)ROWS * EMB * 2);
  u16*      wqkvT  = (u16*)take((size_t)1536 * 512 * 2);
  u16*      w1T    = (u16*)take((size_t)2048 * 512 * 2);
  u16*      Qb     = (u16*)take((size_t)MB * NH * SEQ * HD * 2);
  u16*      Kb     = (u16*)take((size_t)MB * NH * SEQ * HD * 2);
  u16*      Vtb    = (u16*)take((size_t)MB * NH * SEQ * HD * 2);
  u16*      att    = (u16*)take((size_t)ROWS * EMB * 2);
  u16*      n2     = (u16*)take((size_t)ROWS * EMB * 2);
  unsigned* spikeL = (unsigned*)take((size_t)CAP * 4);
  unsigned* candL  = (unsigned*)take((size_t)CAP * 4);

  k_prep<<<3840, 256, 0, stream>>>(x, g1, be1, wq, wk, wv, w1, n1, wqkvT, w1T, cnt);
  k_gemm_qkv<<<dim3(12, 64), 256, 0, stream>>>(n1, wqkvT, bq, bk, bv, Qb, Kb, Vtb);
  k_flash<<<dim3(16, 8, 4), 256, 0, stream>>>(Qb, Kb, Vtb, att);
  k_ln2<<<ROWS / 4, 256, 0, stream>>>(x, att, g2, be2, b2, n2, out);
  k_gemm_ffn1<<<dim3(16, 64), 256, 0, stream>>>(n2, w1T, b1, cnt, spikeL, candL);
  k_fixup<<<256, 256, 0, stream>>>(x, att, w1, b1, g2, be2, cnt, spikeL, candL);
  k_apply<<<128, 256, 0, stream>>>(w2, cnt, spikeL, out);
}